// Round 1
// baseline (660.519 us; speedup 1.0000x reference)
//
#include <hip/hip_runtime.h>
#include <hip/hip_bf16.h>

// ---------------------------------------------------------------------------
// 2-layer bidirectional GRU, B=1024 T=512 H=31 IN=36 -> last step -> FC(62->7)
//
// Design (round 1):
//  * L1 backward = ONE GRU step at t=T-1 (ys[:, ::-1][:, -1] == scan step 0).
//  * L1 forward: full scan but only final h needed -> no y writes.
//  * Scan kernels: 1 wave per (batch, dir). 64 lanes = 32 units x 2 halves,
//    k-dim split across halves, combined with __shfl_xor(.,32).
//    h kept in LDS per wave (wave-local => NO barriers in the 512-step loop).
//    xg (input gates) fused into the scan: Wih row-slices live in VGPRs.
//    x / y0 rows prefetched (double-buffered float2 broadcast loads).
//  * ws layout: y0 (B,T,62) + hf (B,31). fp32 path if ws >= 131MB,
//    bf16-y0 fallback if ws >= 66MB, else probe-only (fails but informative).
//  * ws_probe_* kernel name encodes ws_size bracket for future rounds.
// ---------------------------------------------------------------------------

#define NB 1024
#define NT 512
#define NH 31
#define NG 93
#define NC 7

__device__ __forceinline__ float sig_(float x) { return 1.f / (1.f + __expf(-x)); }
__device__ __forceinline__ float th_(float x)  { float e = __expf(2.f * x); return (e - 1.f) / (e + 1.f); }

__device__ __forceinline__ float tf_(float v) { return v; }
__device__ __forceinline__ float tf_(__hip_bfloat16 v) { return __bfloat162float(v); }

__device__ __forceinline__ void ldpair(const float* p, float& a, float& b) {
    float2 v = *(const float2*)p; a = v.x; b = v.y;
}
__device__ __forceinline__ void ldpair(const __hip_bfloat16* p, float& a, float& b) {
    ushort2 u = *(const ushort2*)p;
    a = __uint_as_float((unsigned)u.x << 16);
    b = __uint_as_float((unsigned)u.y << 16);
}
__device__ __forceinline__ void stoy(float* p, float v) { *p = v; }
__device__ __forceinline__ void stoy(__hip_bfloat16* p, float v) { *p = __float2bfloat16(v); }

// XT: input element type (x or y0), YT: y0 store type.
// HLA = half0 k-count (== klo of half1), HLB = half1 k-count. Both even.
template<typename XT, typename YT, int DIN, int HLA, int HLB, bool WRITE_Y, bool WRITE_HF>
__device__ __forceinline__ void gru_scan_body(
    const XT* __restrict__ xin,
    const float* __restrict__ Wih, const float* __restrict__ Whh,
    const float* __restrict__ bih, const float* __restrict__ bhh,
    int dir, YT* __restrict__ y, float* __restrict__ hf)
{
    static_assert((HLA & 1) == 0 && (HLB & 1) == 0, "even halves");
    const int tid  = threadIdx.x;
    const int w    = tid >> 6;          // wave in block (0..3) == batch slot
    const int lane = tid & 63;
    const int half = lane >> 5;
    const int j    = lane & 31;         // hidden unit (valid j < 31)
    const int jj   = j < NH ? j : NH - 1;
    const int b    = blockIdx.x * 4 + w;

    __shared__ __align__(16) float hbuf[4][32];
    if (lane < 32) hbuf[w][lane] = 0.f;   // includes pad slot [31] = 0
    __syncthreads();

    const int klo  = half ? HLA : 0;
    const int kcnt = half ? HLB : HLA;

    // Wih slices (rows jj, NH+jj, 2NH+jj ; cols klo..klo+kcnt) in VGPRs
    float Wxr[HLA], Wxz[HLA], Wxn[HLA];
#pragma unroll
    for (int k = 0; k < HLA; ++k) {
        const bool v = k < kcnt;
        Wxr[k] = v ? Wih[(0 * NH + jj) * DIN + klo + k] : 0.f;
        Wxz[k] = v ? Wih[(1 * NH + jj) * DIN + klo + k] : 0.f;
        Wxn[k] = v ? Wih[(2 * NH + jj) * DIN + klo + k] : 0.f;
    }
    // Whh slices: half0 cols 0..15, half1 cols 16..31 (col 31 zero-padded)
    const int hlo = half * 16;
    float Whr[16], Whz[16], Whn[16];
#pragma unroll
    for (int k = 0; k < 16; ++k) {
        const bool v = (hlo + k) < NH;
        Whr[k] = v ? Whh[(0 * NH + jj) * NH + hlo + k] : 0.f;
        Whz[k] = v ? Whh[(1 * NH + jj) * NH + hlo + k] : 0.f;
        Whn[k] = v ? Whh[(2 * NH + jj) * NH + hlo + k] : 0.f;
    }
    // biases only on half0 (summed once after the xor-combine)
    float b_r = 0.f, b_z = 0.f, b_xn = 0.f, b_hn = 0.f;
    if (half == 0) {
        b_r  = bih[jj] + bhh[jj];
        b_z  = bih[NH + jj] + bhh[NH + jj];
        b_xn = bih[2 * NH + jj];
        b_hn = bhh[2 * NH + jj];
    }

    const XT* xbase = xin + (size_t)b * NT * DIN + klo;
    YT* ybase = nullptr;
    if (WRITE_Y) ybase = y + (size_t)b * NT * 62 + dir * NH + j;

    float h_prev = 0.f;
    float xa[HLA], xb[HLA];
#pragma unroll
    for (int k = 0; k < HLA; ++k) { xa[k] = 0.f; xb[k] = 0.f; }

    // prefetch step 0
    {
        const int t0 = dir ? NT - 1 : 0;
        const XT* p = xbase + (size_t)t0 * DIN;
#pragma unroll
        for (int k = 0; k < HLA; k += 2)
            if (k < kcnt) ldpair(p + k, xa[k], xa[k + 1]);
    }

    auto step = [&](float (&xv)[HLA], int s) {
        const float4 h0 = *(const float4*)&hbuf[w][hlo + 0];
        const float4 h1 = *(const float4*)&hbuf[w][hlo + 4];
        const float4 h2 = *(const float4*)&hbuf[w][hlo + 8];
        const float4 h3 = *(const float4*)&hbuf[w][hlo + 12];
        const float hs[16] = { h0.x, h0.y, h0.z, h0.w, h1.x, h1.y, h1.z, h1.w,
                               h2.x, h2.y, h2.z, h2.w, h3.x, h3.y, h3.z, h3.w };
        float ar = b_r, az = b_z, an = b_xn, ah = b_hn;
#pragma unroll
        for (int k = 0; k < HLA; ++k) {
            ar = fmaf(Wxr[k], xv[k], ar);
            az = fmaf(Wxz[k], xv[k], az);
            an = fmaf(Wxn[k], xv[k], an);
        }
#pragma unroll
        for (int k = 0; k < 16; ++k) {
            ar = fmaf(Whr[k], hs[k], ar);
            az = fmaf(Whz[k], hs[k], az);
            ah = fmaf(Whn[k], hs[k], ah);
        }
        ar += __shfl_xor(ar, 32, 64);
        az += __shfl_xor(az, 32, 64);
        an += __shfl_xor(an, 32, 64);
        ah += __shfl_xor(ah, 32, 64);
        const float r = sig_(ar);
        const float z = sig_(az);
        const float n = th_(an + r * ah);
        const float hnew = n + z * (h_prev - n);
        h_prev = hnew;
        if (half == 0 && j < NH) {
            hbuf[w][j] = hnew;
            if (WRITE_Y) {
                const int t = dir ? NT - 1 - s : s;
                stoy(ybase + (size_t)t * 62, hnew);
            }
        }
    };

    for (int s = 0; s < NT; s += 2) {
        {   // compute step s with xa, prefetch s+1 into xb
            const int sn = s + 1;
            const int tn = dir ? NT - 1 - sn : sn;
            const XT* p = xbase + (size_t)tn * DIN;
#pragma unroll
            for (int k = 0; k < HLA; k += 2)
                if (k < kcnt) ldpair(p + k, xb[k], xb[k + 1]);
            step(xa, s);
        }
        {   // compute step s+1 with xb, prefetch s+2 into xa (clamped)
            int sn = s + 2; if (sn >= NT) sn = NT - 1;
            const int tn = dir ? NT - 1 - sn : sn;
            const XT* p = xbase + (size_t)tn * DIN;
#pragma unroll
            for (int k = 0; k < HLA; k += 2)
                if (k < kcnt) ldpair(p + k, xa[k], xa[k + 1]);
            step(xb, s + 1);
        }
    }
    if (WRITE_HF && half == 0 && j < NH) hf[b * NH + j] = h_prev;
}

template<typename YT>
__global__ void __launch_bounds__(256, 2) gru_scan_l0(
    const float* __restrict__ x,
    const float* __restrict__ Wf, const float* __restrict__ Uf,
    const float* __restrict__ bf, const float* __restrict__ cf,
    const float* __restrict__ Wb, const float* __restrict__ Ub,
    const float* __restrict__ bb, const float* __restrict__ cb,
    YT* __restrict__ y)
{
    if (blockIdx.y == 0)
        gru_scan_body<float, YT, 36, 18, 18, true, false>(x, Wf, Uf, bf, cf, 0, y, nullptr);
    else
        gru_scan_body<float, YT, 36, 18, 18, true, false>(x, Wb, Ub, bb, cb, 1, y, nullptr);
}

template<typename YT>
__global__ void __launch_bounds__(256, 1) gru_scan_l1(
    const YT* __restrict__ y0,
    const float* __restrict__ W, const float* __restrict__ U,
    const float* __restrict__ bi, const float* __restrict__ bh,
    float* __restrict__ hf)
{
    gru_scan_body<YT, YT, 62, 32, 30, false, true>(y0, W, U, bi, bh, 0, (YT*)nullptr, hf);
}

// L1 backward single step at t=T-1 (h0=0) + FC. One wave per batch.
template<typename YT>
__global__ void __launch_bounds__(64, 4) gru_final(
    const YT* __restrict__ y0, const float* __restrict__ hf,
    const float* __restrict__ Wih1b, const float* __restrict__ bih1b,
    const float* __restrict__ bhh1b,
    const float* __restrict__ fcw, const float* __restrict__ fcb,
    float* __restrict__ out)
{
    const int b = blockIdx.x;
    const int lane = threadIdx.x;
    __shared__ float row[62];
    __shared__ float xg[NG];
    __shared__ float last[62];
    const YT* yl = y0 + ((size_t)b * NT + (NT - 1)) * 62;
    if (lane < 62) row[lane] = tf_(yl[lane]);
    __syncthreads();
    for (int g = lane; g < NG; g += 64) {
        float a = bih1b[g];
        const float* wr = Wih1b + g * 62;
#pragma unroll
        for (int k = 0; k < 62; ++k) a = fmaf(wr[k], row[k], a);
        xg[g] = a;
    }
    if (lane < NH) last[lane] = hf[b * NH + lane];
    __syncthreads();
    if (lane < NH) {
        const float r = sig_(xg[lane] + bhh1b[lane]);
        const float z = sig_(xg[NH + lane] + bhh1b[NH + lane]);
        const float n = th_(xg[2 * NH + lane] + r * bhh1b[2 * NH + lane]);
        last[NH + lane] = (1.f - z) * n;   // + z*h0, h0 = 0
    }
    __syncthreads();
    if (lane < NC) {
        float a = fcb[lane];
        const float* wr = fcw + lane * 62;
#pragma unroll
        for (int k = 0; k < 62; ++k) a = fmaf(wr[k], last[k], a);
        out[b * NC + lane] = a;
    }
}

// ws_size bracket probes (name shows up in rocprof dispatch list)
#define WS_PROBE(name) \
__global__ void name(float* p) { \
    float a = 1.0f; const float m = 1.0000001f; \
    for (int i = 0; i < 3000; ++i) a = fmaf(a, m, 1.0f); \
    if (a < -1e30f) p[0] = a; \
}
WS_PROBE(ws_lt_64mb)
WS_PROBE(ws_64_128mb)
WS_PROBE(ws_128_256mb)
WS_PROBE(ws_256_512mb)
WS_PROBE(ws_512_1024mb)
WS_PROBE(ws_ge_1gb)

extern "C" void kernel_launch(void* const* d_in, const int* in_sizes, int n_in,
                              void* d_out, int out_size, void* d_ws, size_t ws_size,
                              hipStream_t stream)
{
    const float* x     = (const float*)d_in[0];
    const float* Wih0f = (const float*)d_in[1];
    const float* Whh0f = (const float*)d_in[2];
    const float* bih0f = (const float*)d_in[3];
    const float* bhh0f = (const float*)d_in[4];
    const float* Wih0b = (const float*)d_in[5];
    const float* Whh0b = (const float*)d_in[6];
    const float* bih0b = (const float*)d_in[7];
    const float* bhh0b = (const float*)d_in[8];
    const float* Wih1f = (const float*)d_in[9];
    const float* Whh1f = (const float*)d_in[10];
    const float* bih1f = (const float*)d_in[11];
    const float* bhh1f = (const float*)d_in[12];
    const float* Wih1b = (const float*)d_in[13];
    const float* Whh1b = (const float*)d_in[14];  // unused (single step from h0=0 uses only bhh)
    const float* bih1b = (const float*)d_in[15];
    const float* bhh1b = (const float*)d_in[16];
    const float* fcw   = (const float*)d_in[17];
    const float* fcb   = (const float*)d_in[18];
    float* out = (float*)d_out;
    (void)Whh1b; (void)in_sizes; (void)n_in; (void)out_size;

    const size_t y0_elems   = (size_t)NB * NT * 62;
    const size_t hf_bytes   = (size_t)NB * NH * 4;
    const size_t need_f32   = y0_elems * 4 + 256 + hf_bytes;
    const size_t need_bf16  = y0_elems * 2 + 256 + hf_bytes;

    const dim3 blk(256);
    if (ws_size >= need_f32) {
        float* y0 = (float*)d_ws;
        float* hf = (float*)((char*)d_ws + ((y0_elems * 4 + 255) & ~(size_t)255));
        gru_scan_l0<float><<<dim3(NB / 4, 2), blk, 0, stream>>>(
            x, Wih0f, Whh0f, bih0f, bhh0f, Wih0b, Whh0b, bih0b, bhh0b, y0);
        gru_scan_l1<float><<<dim3(NB / 4, 1), blk, 0, stream>>>(
            y0, Wih1f, Whh1f, bih1f, bhh1f, hf);
        gru_final<float><<<dim3(NB), dim3(64), 0, stream>>>(
            y0, hf, Wih1b, bih1b, bhh1b, fcw, fcb, out);
    } else if (ws_size >= need_bf16) {
        __hip_bfloat16* y0 = (__hip_bfloat16*)d_ws;
        float* hf = (float*)((char*)d_ws + ((y0_elems * 2 + 255) & ~(size_t)255));
        gru_scan_l0<__hip_bfloat16><<<dim3(NB / 4, 2), blk, 0, stream>>>(
            x, Wih0f, Whh0f, bih0f, bhh0f, Wih0b, Whh0b, bih0b, bhh0b, y0);
        gru_scan_l1<__hip_bfloat16><<<dim3(NB / 4, 1), blk, 0, stream>>>(
            y0, Wih1f, Whh1f, bih1f, bhh1f, hf);
        gru_final<__hip_bfloat16><<<dim3(NB), dim3(64), 0, stream>>>(
            y0, hf, Wih1b, bih1b, bhh1b, fcw, fcb, out);
    }
    // ws bracket probe (shows in rocprof dispatch list; ~2-5us)
    float* wp = (float*)d_ws;
    const size_t mb = ws_size >> 20;
    if      (mb < 64)   ws_lt_64mb    <<<1, 64, 0, stream>>>(wp);
    else if (mb < 128)  ws_64_128mb   <<<1, 64, 0, stream>>>(wp);
    else if (mb < 256)  ws_128_256mb  <<<1, 64, 0, stream>>>(wp);
    else if (mb < 512)  ws_256_512mb  <<<1, 64, 0, stream>>>(wp);
    else if (mb < 1024) ws_512_1024mb <<<1, 64, 0, stream>>>(wp);
    else                ws_ge_1gb     <<<1, 64, 0, stream>>>(wp);
}

// Round 2
// 563.022 us; speedup vs baseline: 1.1732x; 1.1732x over previous
//
#include <hip/hip_runtime.h>
#include <hip/hip_bf16.h>

// ---------------------------------------------------------------------------
// 2-layer bidirectional GRU, B=1024 T=512 H=31 IN=36 -> last step -> FC(62->7)
//
// Round 2: fix the register spill (VGPR_Count was 84 => weight arrays lived
// in scratch; caused by lambda reference-capture taking array addresses).
//  * step body is now a macro (no address-taking), all unrolled loops have
//    compile-time trip counts, weights/x-prefetch stay in VGPRs.
//  * l0 k-split 18+18 exact; l1 k-split 32+32 (half0 pads 2 zero weights,
//    loads stay in-bounds: half0 reads k0..31, half1 reads k30..61 of 62).
//  * pointer-increment addressing (no per-step index muls).
//  * structure unchanged: 1 wave per (batch,dir); 64 lanes = 32 units x 2
//    k-halves combined via __shfl_xor(.,32); h in wave-local LDS (no
//    barriers inside the 512-step loop); double-buffered x prefetch.
//  * L1 backward = ONE GRU step at t=T-1 (only last timestep is consumed).
// ---------------------------------------------------------------------------

#define NB 1024
#define NT 512
#define NH 31
#define NG 93
#define NC 7

__device__ __forceinline__ float sig_(float x) { return 1.f / (1.f + __expf(-x)); }
__device__ __forceinline__ float th_(float x)  { float e = __expf(2.f * x); return (e - 1.f) / (e + 1.f); }

__device__ __forceinline__ float tf_(float v) { return v; }
__device__ __forceinline__ float tf_(__hip_bfloat16 v) { return __bfloat162float(v); }

__device__ __forceinline__ void ldpair(const float* p, float& a, float& b) {
    float2 v = *(const float2*)p; a = v.x; b = v.y;
}
__device__ __forceinline__ void ldpair(const __hip_bfloat16* p, float& a, float& b) {
    ushort2 u = *(const ushort2*)p;
    a = __uint_as_float((unsigned)u.x << 16);
    b = __uint_as_float((unsigned)u.y << 16);
}
__device__ __forceinline__ void stoy(float* p, float v) { *p = v; }
__device__ __forceinline__ void stoy(__hip_bfloat16* p, float v) { *p = __float2bfloat16(v); }

#define LOADX(arr, ptr)                                                   \
    _Pragma("unroll") for (int k_ = 0; k_ < KH; k_ += 2)                  \
        ldpair((ptr) + k_, arr[k_], arr[k_ + 1])

#define GRU_STEP(XV)                                                      \
    do {                                                                  \
        const float4 g0 = *(const float4*)&hbuf[w][hlo + 0];              \
        const float4 g1 = *(const float4*)&hbuf[w][hlo + 4];              \
        const float4 g2 = *(const float4*)&hbuf[w][hlo + 8];              \
        const float4 g3 = *(const float4*)&hbuf[w][hlo + 12];             \
        float hv[16];                                                     \
        hv[0]=g0.x;  hv[1]=g0.y;  hv[2]=g0.z;  hv[3]=g0.w;                \
        hv[4]=g1.x;  hv[5]=g1.y;  hv[6]=g1.z;  hv[7]=g1.w;                \
        hv[8]=g2.x;  hv[9]=g2.y;  hv[10]=g2.z; hv[11]=g2.w;               \
        hv[12]=g3.x; hv[13]=g3.y; hv[14]=g3.z; hv[15]=g3.w;               \
        float ar = b_r, az = b_z, an = b_xn, ah = b_hn;                   \
        _Pragma("unroll") for (int k_ = 0; k_ < KH; ++k_) {               \
            ar = fmaf(Wxr[k_], XV[k_], ar);                               \
            az = fmaf(Wxz[k_], XV[k_], az);                               \
            an = fmaf(Wxn[k_], XV[k_], an);                               \
        }                                                                 \
        _Pragma("unroll") for (int k_ = 0; k_ < 16; ++k_) {               \
            ar = fmaf(Whr[k_], hv[k_], ar);                               \
            az = fmaf(Whz[k_], hv[k_], az);                               \
            ah = fmaf(Whn[k_], hv[k_], ah);                               \
        }                                                                 \
        ar += __shfl_xor(ar, 32, 64);                                     \
        az += __shfl_xor(az, 32, 64);                                     \
        an += __shfl_xor(an, 32, 64);                                     \
        ah += __shfl_xor(ah, 32, 64);                                     \
        const float r_ = sig_(ar);                                        \
        const float z_ = sig_(az);                                        \
        const float n_ = th_(an + r_ * ah);                               \
        h_prev = n_ + z_ * (h_prev - n_);                                 \
        if (half == 0 && j < NH) {                                        \
            hbuf[w][j] = h_prev;                                          \
            if (WRITE_Y) stoy(yp, h_prev);                                \
        }                                                                 \
    } while (0)

// XT: input elem type, YT: y0 store type. KH: per-half k-count (compile-time).
// half0 covers k in [0, DIN-KH) plus zero-pad to KH; half1 covers [DIN-KH, DIN).
template<typename XT, typename YT, int DIN, int KH, bool WRITE_Y, bool WRITE_HF>
__device__ __forceinline__ void gru_scan_body(
    const XT* __restrict__ xin,
    const float* __restrict__ Wih, const float* __restrict__ Whh,
    const float* __restrict__ bih, const float* __restrict__ bhh,
    int dir, YT* __restrict__ y, float* __restrict__ hf)
{
    static_assert((KH & 1) == 0, "even KH");
    const int tid  = threadIdx.x;
    const int w    = tid >> 6;
    const int lane = tid & 63;
    const int half = lane >> 5;
    const int j    = lane & 31;
    const int jj   = j < NH ? j : NH - 1;
    const int b    = blockIdx.x * 4 + w;

    __shared__ __align__(16) float hbuf[4][32];
    if (lane < 32) hbuf[w][lane] = 0.f;
    __syncthreads();

    const int klo = half ? (DIN - KH) : 0;

    // Wih row-slices in VGPRs. half0 valid for k < DIN-KH (l0: all 18; l1: 30).
    float Wxr[KH], Wxz[KH], Wxn[KH];
#pragma unroll
    for (int k = 0; k < KH; ++k) {
        const bool v = half ? true : (k < DIN - KH);
        Wxr[k] = v ? Wih[(0 * NH + jj) * DIN + klo + k] : 0.f;
        Wxz[k] = v ? Wih[(1 * NH + jj) * DIN + klo + k] : 0.f;
        Wxn[k] = v ? Wih[(2 * NH + jj) * DIN + klo + k] : 0.f;
    }
    const int hlo = half * 16;
    float Whr[16], Whz[16], Whn[16];
#pragma unroll
    for (int k = 0; k < 16; ++k) {
        const bool v = (hlo + k) < NH;
        Whr[k] = v ? Whh[(0 * NH + jj) * NH + hlo + k] : 0.f;
        Whz[k] = v ? Whh[(1 * NH + jj) * NH + hlo + k] : 0.f;
        Whn[k] = v ? Whh[(2 * NH + jj) * NH + hlo + k] : 0.f;
    }
    // biases only on half0 (summed once; shfl_xor sum delivers to both halves)
    float b_r = 0.f, b_z = 0.f, b_xn = 0.f, b_hn = 0.f;
    if (half == 0) {
        b_r  = bih[jj] + bhh[jj];
        b_z  = bih[NH + jj] + bhh[NH + jj];
        b_xn = bih[2 * NH + jj];
        b_hn = bhh[2 * NH + jj];
    }

    const XT* xrow = xin + (size_t)b * NT * DIN + klo
                   + (dir ? (size_t)(NT - 1) * DIN : 0);
    const ptrdiff_t xstep = dir ? -DIN : DIN;
    YT* yp = nullptr;
    ptrdiff_t ystep = 0;
    if (WRITE_Y) {
        yp = y + (size_t)b * NT * 62 + dir * NH + j
           + (dir ? (size_t)(NT - 1) * 62 : 0);
        ystep = dir ? -62 : 62;
    }

    float h_prev = 0.f;
    float xa[KH], xb[KH];
    LOADX(xa, xrow);
    const XT* xpre = xrow + xstep;

    for (int s = 0; s < NT; s += 2) {
        LOADX(xb, xpre);                       // row s+1
        if (s + 2 < NT) xpre += xstep;         // -> row s+2 (clamped)
        GRU_STEP(xa);                          // step s
        if (WRITE_Y) yp += ystep;
        LOADX(xa, xpre);                       // row s+2 (or clamp re-read)
        if (s + 3 < NT) xpre += xstep;         // -> row s+3
        GRU_STEP(xb);                          // step s+1
        if (WRITE_Y) yp += ystep;
    }
    if (WRITE_HF && half == 0 && j < NH) hf[b * NH + j] = h_prev;
}

template<typename YT>
__global__ void __launch_bounds__(256, 2) gru_scan_l0(
    const float* __restrict__ x,
    const float* __restrict__ Wf, const float* __restrict__ Uf,
    const float* __restrict__ bf, const float* __restrict__ cf,
    const float* __restrict__ Wb, const float* __restrict__ Ub,
    const float* __restrict__ bb, const float* __restrict__ cb,
    YT* __restrict__ y)
{
    if (blockIdx.y == 0)
        gru_scan_body<float, YT, 36, 18, true, false>(x, Wf, Uf, bf, cf, 0, y, nullptr);
    else
        gru_scan_body<float, YT, 36, 18, true, false>(x, Wb, Ub, bb, cb, 1, y, nullptr);
}

template<typename YT>
__global__ void __launch_bounds__(256, 1) gru_scan_l1(
    const YT* __restrict__ y0,
    const float* __restrict__ W, const float* __restrict__ U,
    const float* __restrict__ bi, const float* __restrict__ bh,
    float* __restrict__ hf)
{
    gru_scan_body<YT, YT, 62, 32, false, true>(y0, W, U, bi, bh, 0, (YT*)nullptr, hf);
}

// L1 backward single step at t=T-1 (h0=0) + FC. One wave per batch.
template<typename YT>
__global__ void __launch_bounds__(64, 4) gru_final(
    const YT* __restrict__ y0, const float* __restrict__ hf,
    const float* __restrict__ Wih1b, const float* __restrict__ bih1b,
    const float* __restrict__ bhh1b,
    const float* __restrict__ fcw, const float* __restrict__ fcb,
    float* __restrict__ out)
{
    const int b = blockIdx.x;
    const int lane = threadIdx.x;
    __shared__ float row[62];
    __shared__ float xg[NG];
    __shared__ float last[62];
    const YT* yl = y0 + ((size_t)b * NT + (NT - 1)) * 62;
    if (lane < 62) row[lane] = tf_(yl[lane]);
    __syncthreads();
    for (int g = lane; g < NG; g += 64) {
        float a = bih1b[g];
        const float* wr = Wih1b + g * 62;
#pragma unroll
        for (int k = 0; k < 62; ++k) a = fmaf(wr[k], row[k], a);
        xg[g] = a;
    }
    if (lane < NH) last[lane] = hf[b * NH + lane];
    __syncthreads();
    if (lane < NH) {
        const float r = sig_(xg[lane] + bhh1b[lane]);
        const float z = sig_(xg[NH + lane] + bhh1b[NH + lane]);
        const float n = th_(xg[2 * NH + lane] + r * bhh1b[2 * NH + lane]);
        last[NH + lane] = (1.f - z) * n;   // + z*h0, h0 = 0
    }
    __syncthreads();
    if (lane < NC) {
        float a = fcb[lane];
        const float* wr = fcw + lane * 62;
#pragma unroll
        for (int k = 0; k < 62; ++k) a = fmaf(wr[k], last[k], a);
        out[b * NC + lane] = a;
    }
}

extern "C" void kernel_launch(void* const* d_in, const int* in_sizes, int n_in,
                              void* d_out, int out_size, void* d_ws, size_t ws_size,
                              hipStream_t stream)
{
    const float* x     = (const float*)d_in[0];
    const float* Wih0f = (const float*)d_in[1];
    const float* Whh0f = (const float*)d_in[2];
    const float* bih0f = (const float*)d_in[3];
    const float* bhh0f = (const float*)d_in[4];
    const float* Wih0b = (const float*)d_in[5];
    const float* Whh0b = (const float*)d_in[6];
    const float* bih0b = (const float*)d_in[7];
    const float* bhh0b = (const float*)d_in[8];
    const float* Wih1f = (const float*)d_in[9];
    const float* Whh1f = (const float*)d_in[10];
    const float* bih1f = (const float*)d_in[11];
    const float* bhh1f = (const float*)d_in[12];
    const float* Wih1b = (const float*)d_in[13];
    const float* Whh1b = (const float*)d_in[14];  // unused: single step from h0=0
    const float* bih1b = (const float*)d_in[15];
    const float* bhh1b = (const float*)d_in[16];
    const float* fcw   = (const float*)d_in[17];
    const float* fcb   = (const float*)d_in[18];
    float* out = (float*)d_out;
    (void)Whh1b; (void)in_sizes; (void)n_in; (void)out_size;

    const size_t y0_elems  = (size_t)NB * NT * 62;
    const size_t hf_bytes  = (size_t)NB * NH * 4;
    const size_t need_f32  = y0_elems * 4 + 256 + hf_bytes;
    const size_t need_bf16 = y0_elems * 2 + 256 + hf_bytes;

    const dim3 blk(256);
    if (ws_size >= need_f32) {
        float* y0 = (float*)d_ws;
        float* hf = (float*)((char*)d_ws + ((y0_elems * 4 + 255) & ~(size_t)255));
        gru_scan_l0<float><<<dim3(NB / 4, 2), blk, 0, stream>>>(
            x, Wih0f, Whh0f, bih0f, bhh0f, Wih0b, Whh0b, bih0b, bhh0b, y0);
        gru_scan_l1<float><<<dim3(NB / 4, 1), blk, 0, stream>>>(
            y0, Wih1f, Whh1f, bih1f, bhh1f, hf);
        gru_final<float><<<dim3(NB), dim3(64), 0, stream>>>(
            y0, hf, Wih1b, bih1b, bhh1b, fcw, fcb, out);
    } else if (ws_size >= need_bf16) {
        __hip_bfloat16* y0 = (__hip_bfloat16*)d_ws;
        float* hf = (float*)((char*)d_ws + ((y0_elems * 2 + 255) & ~(size_t)255));
        gru_scan_l0<__hip_bfloat16><<<dim3(NB / 4, 2), blk, 0, stream>>>(
            x, Wih0f, Whh0f, bih0f, bhh0f, Wih0b, Whh0b, bih0b, bhh0b, y0);
        gru_scan_l1<__hip_bfloat16><<<dim3(NB / 4, 1), blk, 0, stream>>>(
            y0, Wih1f, Whh1f, bih1f, bhh1f, hf);
        gru_final<__hip_bfloat16><<<dim3(NB), dim3(64), 0, stream>>>(
            y0, hf, Wih1b, bih1b, bhh1b, fcw, fcb, out);
    }
}

// Round 3
// 556.753 us; speedup vs baseline: 1.1864x; 1.0113x over previous
//
#include <hip/hip_runtime.h>
#include <hip/hip_bf16.h>

// ---------------------------------------------------------------------------
// 2-layer bidirectional GRU, B=1024 T=512 H=31 IN=36 -> last step -> FC(62->7)
//
// Round 3: kill the spill-for-occupancy. VGPR_Count=84 (~512/6) showed the
// allocator targeted 6 waves/EU while the grid only ever provides 2 (l0) / 1
// (l1) waves per SIMD. __launch_bounds__'s 2nd arg only sets the MIN
// waves/EU; use amdgpu_waves_per_eu(min,max) to pin BOTH so the allocator
// keeps the ~190 live weight/prefetch floats in VGPRs.
//  * l0: waves_per_eu(2,2) -> 256-VGPR budget.  l1: (1,1) -> 512.
//  * structure unchanged: 1 wave per (batch,dir); 64 lanes = 32 units x 2
//    k-halves combined via __shfl_xor(.,32); h in wave-local LDS (no
//    barriers inside the 512-step loop); double-buffered x prefetch.
//  * L1 backward = ONE GRU step at t=T-1 (only last timestep is consumed).
// ---------------------------------------------------------------------------

#define NB 1024
#define NT 512
#define NH 31
#define NG 93
#define NC 7

__device__ __forceinline__ float sig_(float x) { return 1.f / (1.f + __expf(-x)); }
__device__ __forceinline__ float th_(float x)  { float e = __expf(2.f * x); return (e - 1.f) / (e + 1.f); }

__device__ __forceinline__ float tf_(float v) { return v; }
__device__ __forceinline__ float tf_(__hip_bfloat16 v) { return __bfloat162float(v); }

__device__ __forceinline__ void ldpair(const float* p, float& a, float& b) {
    float2 v = *(const float2*)p; a = v.x; b = v.y;
}
__device__ __forceinline__ void ldpair(const __hip_bfloat16* p, float& a, float& b) {
    ushort2 u = *(const ushort2*)p;
    a = __uint_as_float((unsigned)u.x << 16);
    b = __uint_as_float((unsigned)u.y << 16);
}
__device__ __forceinline__ void stoy(float* p, float v) { *p = v; }
__device__ __forceinline__ void stoy(__hip_bfloat16* p, float v) { *p = __float2bfloat16(v); }

#define LOADX(arr, ptr)                                                   \
    _Pragma("unroll") for (int k_ = 0; k_ < KH; k_ += 2)                  \
        ldpair((ptr) + k_, arr[k_], arr[k_ + 1])

#define GRU_STEP(XV)                                                      \
    do {                                                                  \
        const float4 g0 = *(const float4*)&hbuf[w][hlo + 0];              \
        const float4 g1 = *(const float4*)&hbuf[w][hlo + 4];              \
        const float4 g2 = *(const float4*)&hbuf[w][hlo + 8];              \
        const float4 g3 = *(const float4*)&hbuf[w][hlo + 12];             \
        float hv[16];                                                     \
        hv[0]=g0.x;  hv[1]=g0.y;  hv[2]=g0.z;  hv[3]=g0.w;                \
        hv[4]=g1.x;  hv[5]=g1.y;  hv[6]=g1.z;  hv[7]=g1.w;                \
        hv[8]=g2.x;  hv[9]=g2.y;  hv[10]=g2.z; hv[11]=g2.w;               \
        hv[12]=g3.x; hv[13]=g3.y; hv[14]=g3.z; hv[15]=g3.w;               \
        float ar = b_r, az = b_z, an = b_xn, ah = b_hn;                   \
        _Pragma("unroll") for (int k_ = 0; k_ < KH; ++k_) {               \
            ar = fmaf(Wxr[k_], XV[k_], ar);                               \
            az = fmaf(Wxz[k_], XV[k_], az);                               \
            an = fmaf(Wxn[k_], XV[k_], an);                               \
        }                                                                 \
        _Pragma("unroll") for (int k_ = 0; k_ < 16; ++k_) {               \
            ar = fmaf(Whr[k_], hv[k_], ar);                               \
            az = fmaf(Whz[k_], hv[k_], az);                               \
            ah = fmaf(Whn[k_], hv[k_], ah);                               \
        }                                                                 \
        ar += __shfl_xor(ar, 32, 64);                                     \
        az += __shfl_xor(az, 32, 64);                                     \
        an += __shfl_xor(an, 32, 64);                                     \
        ah += __shfl_xor(ah, 32, 64);                                     \
        const float r_ = sig_(ar);                                        \
        const float z_ = sig_(az);                                        \
        const float n_ = th_(an + r_ * ah);                               \
        h_prev = n_ + z_ * (h_prev - n_);                                 \
        if (half == 0 && j < NH) {                                        \
            hbuf[w][j] = h_prev;                                          \
            if (WRITE_Y) stoy(yp, h_prev);                                \
        }                                                                 \
    } while (0)

// XT: input elem type, YT: y0 store type. KH: per-half k-count (compile-time).
// half0 covers k in [0, DIN-KH) plus zero-pad to KH; half1 covers [DIN-KH, DIN).
template<typename XT, typename YT, int DIN, int KH, bool WRITE_Y, bool WRITE_HF>
__device__ __forceinline__ void gru_scan_body(
    const XT* __restrict__ xin,
    const float* __restrict__ Wih, const float* __restrict__ Whh,
    const float* __restrict__ bih, const float* __restrict__ bhh,
    int dir, YT* __restrict__ y, float* __restrict__ hf)
{
    static_assert((KH & 1) == 0, "even KH");
    const int tid  = threadIdx.x;
    const int w    = tid >> 6;
    const int lane = tid & 63;
    const int half = lane >> 5;
    const int j    = lane & 31;
    const int jj   = j < NH ? j : NH - 1;
    const int b    = blockIdx.x * 4 + w;

    __shared__ __align__(16) float hbuf[4][32];
    if (lane < 32) hbuf[w][lane] = 0.f;
    __syncthreads();

    const int klo = half ? (DIN - KH) : 0;

    // Wih row-slices in VGPRs. half0 valid for k < DIN-KH (l0: all 18; l1: 30).
    float Wxr[KH], Wxz[KH], Wxn[KH];
#pragma unroll
    for (int k = 0; k < KH; ++k) {
        const bool v = half ? true : (k < DIN - KH);
        Wxr[k] = v ? Wih[(0 * NH + jj) * DIN + klo + k] : 0.f;
        Wxz[k] = v ? Wih[(1 * NH + jj) * DIN + klo + k] : 0.f;
        Wxn[k] = v ? Wih[(2 * NH + jj) * DIN + klo + k] : 0.f;
    }
    const int hlo = half * 16;
    float Whr[16], Whz[16], Whn[16];
#pragma unroll
    for (int k = 0; k < 16; ++k) {
        const bool v = (hlo + k) < NH;
        Whr[k] = v ? Whh[(0 * NH + jj) * NH + hlo + k] : 0.f;
        Whz[k] = v ? Whh[(1 * NH + jj) * NH + hlo + k] : 0.f;
        Whn[k] = v ? Whh[(2 * NH + jj) * NH + hlo + k] : 0.f;
    }
    // biases only on half0 (summed once; shfl_xor sum delivers to both halves)
    float b_r = 0.f, b_z = 0.f, b_xn = 0.f, b_hn = 0.f;
    if (half == 0) {
        b_r  = bih[jj] + bhh[jj];
        b_z  = bih[NH + jj] + bhh[NH + jj];
        b_xn = bih[2 * NH + jj];
        b_hn = bhh[2 * NH + jj];
    }

    const XT* xrow = xin + (size_t)b * NT * DIN + klo
                   + (dir ? (size_t)(NT - 1) * DIN : 0);
    const ptrdiff_t xstep = dir ? -DIN : DIN;
    YT* yp = nullptr;
    ptrdiff_t ystep = 0;
    if (WRITE_Y) {
        yp = y + (size_t)b * NT * 62 + dir * NH + j
           + (dir ? (size_t)(NT - 1) * 62 : 0);
        ystep = dir ? -62 : 62;
    }

    float h_prev = 0.f;
    float xa[KH], xb[KH];
    LOADX(xa, xrow);
    const XT* xpre = xrow + xstep;

    for (int s = 0; s < NT; s += 2) {
        LOADX(xb, xpre);                       // row s+1
        if (s + 2 < NT) xpre += xstep;         // -> row s+2 (clamped)
        GRU_STEP(xa);                          // step s
        if (WRITE_Y) yp += ystep;
        LOADX(xa, xpre);                       // row s+2 (or clamp re-read)
        if (s + 3 < NT) xpre += xstep;         // -> row s+3
        GRU_STEP(xb);                          // step s+1
        if (WRITE_Y) yp += ystep;
    }
    if (WRITE_HF && half == 0 && j < NH) hf[b * NH + j] = h_prev;
}

template<typename YT>
__global__ void __launch_bounds__(256)
__attribute__((amdgpu_waves_per_eu(2, 2)))
gru_scan_l0(
    const float* __restrict__ x,
    const float* __restrict__ Wf, const float* __restrict__ Uf,
    const float* __restrict__ bf, const float* __restrict__ cf,
    const float* __restrict__ Wb, const float* __restrict__ Ub,
    const float* __restrict__ bb, const float* __restrict__ cb,
    YT* __restrict__ y)
{
    const int d = blockIdx.y;
    gru_scan_body<float, YT, 36, 18, true, false>(
        x, d ? Wb : Wf, d ? Ub : Uf, d ? bb : bf, d ? cb : cf, d, y, nullptr);
}

template<typename YT>
__global__ void __launch_bounds__(256)
__attribute__((amdgpu_waves_per_eu(1, 1)))
gru_scan_l1(
    const YT* __restrict__ y0,
    const float* __restrict__ W, const float* __restrict__ U,
    const float* __restrict__ bi, const float* __restrict__ bh,
    float* __restrict__ hf)
{
    gru_scan_body<YT, YT, 62, 32, false, true>(y0, W, U, bi, bh, 0, (YT*)nullptr, hf);
}

// L1 backward single step at t=T-1 (h0=0) + FC. One wave per batch.
template<typename YT>
__global__ void __launch_bounds__(64, 4) gru_final(
    const YT* __restrict__ y0, const float* __restrict__ hf,
    const float* __restrict__ Wih1b, const float* __restrict__ bih1b,
    const float* __restrict__ bhh1b,
    const float* __restrict__ fcw, const float* __restrict__ fcb,
    float* __restrict__ out)
{
    const int b = blockIdx.x;
    const int lane = threadIdx.x;
    __shared__ float row[62];
    __shared__ float xg[NG];
    __shared__ float last[62];
    const YT* yl = y0 + ((size_t)b * NT + (NT - 1)) * 62;
    if (lane < 62) row[lane] = tf_(yl[lane]);
    __syncthreads();
    for (int g = lane; g < NG; g += 64) {
        float a = bih1b[g];
        const float* wr = Wih1b + g * 62;
#pragma unroll
        for (int k = 0; k < 62; ++k) a = fmaf(wr[k], row[k], a);
        xg[g] = a;
    }
    if (lane < NH) last[lane] = hf[b * NH + lane];
    __syncthreads();
    if (lane < NH) {
        const float r = sig_(xg[lane] + bhh1b[lane]);
        const float z = sig_(xg[NH + lane] + bhh1b[NH + lane]);
        const float n = th_(xg[2 * NH + lane] + r * bhh1b[2 * NH + lane]);
        last[NH + lane] = (1.f - z) * n;   // + z*h0, h0 = 0
    }
    __syncthreads();
    if (lane < NC) {
        float a = fcb[lane];
        const float* wr = fcw + lane * 62;
#pragma unroll
        for (int k = 0; k < 62; ++k) a = fmaf(wr[k], last[k], a);
        out[b * NC + lane] = a;
    }
}

extern "C" void kernel_launch(void* const* d_in, const int* in_sizes, int n_in,
                              void* d_out, int out_size, void* d_ws, size_t ws_size,
                              hipStream_t stream)
{
    const float* x     = (const float*)d_in[0];
    const float* Wih0f = (const float*)d_in[1];
    const float* Whh0f = (const float*)d_in[2];
    const float* bih0f = (const float*)d_in[3];
    const float* bhh0f = (const float*)d_in[4];
    const float* Wih0b = (const float*)d_in[5];
    const float* Whh0b = (const float*)d_in[6];
    const float* bih0b = (const float*)d_in[7];
    const float* bhh0b = (const float*)d_in[8];
    const float* Wih1f = (const float*)d_in[9];
    const float* Whh1f = (const float*)d_in[10];
    const float* bih1f = (const float*)d_in[11];
    const float* bhh1f = (const float*)d_in[12];
    const float* Wih1b = (const float*)d_in[13];
    const float* Whh1b = (const float*)d_in[14];  // unused: single step from h0=0
    const float* bih1b = (const float*)d_in[15];
    const float* bhh1b = (const float*)d_in[16];
    const float* fcw   = (const float*)d_in[17];
    const float* fcb   = (const float*)d_in[18];
    float* out = (float*)d_out;
    (void)Whh1b; (void)in_sizes; (void)n_in; (void)out_size;

    const size_t y0_elems  = (size_t)NB * NT * 62;
    const size_t hf_bytes  = (size_t)NB * NH * 4;
    const size_t need_f32  = y0_elems * 4 + 256 + hf_bytes;
    const size_t need_bf16 = y0_elems * 2 + 256 + hf_bytes;

    const dim3 blk(256);
    if (ws_size >= need_f32) {
        float* y0 = (float*)d_ws;
        float* hf = (float*)((char*)d_ws + ((y0_elems * 4 + 255) & ~(size_t)255));
        gru_scan_l0<float><<<dim3(NB / 4, 2), blk, 0, stream>>>(
            x, Wih0f, Whh0f, bih0f, bhh0f, Wih0b, Whh0b, bih0b, bhh0b, y0);
        gru_scan_l1<float><<<dim3(NB / 4, 1), blk, 0, stream>>>(
            y0, Wih1f, Whh1f, bih1f, bhh1f, hf);
        gru_final<float><<<dim3(NB), dim3(64), 0, stream>>>(
            y0, hf, Wih1b, bih1b, bhh1b, fcw, fcb, out);
    } else if (ws_size >= need_bf16) {
        __hip_bfloat16* y0 = (__hip_bfloat16*)d_ws;
        float* hf = (float*)((char*)d_ws + ((y0_elems * 2 + 255) & ~(size_t)255));
        gru_scan_l0<__hip_bfloat16><<<dim3(NB / 4, 2), blk, 0, stream>>>(
            x, Wih0f, Whh0f, bih0f, bhh0f, Wih0b, Whh0b, bih0b, bhh0b, y0);
        gru_scan_l1<__hip_bfloat16><<<dim3(NB / 4, 1), blk, 0, stream>>>(
            y0, Wih1f, Whh1f, bih1f, bhh1f, hf);
        gru_final<__hip_bfloat16><<<dim3(NB), dim3(64), 0, stream>>>(
            y0, hf, Wih1b, bih1b, bhh1b, fcw, fcb, out);
    }
}